// Round 11
// baseline (293.611 us; speedup 1.0000x reference)
//
#include <hip/hip_runtime.h>

// ---------------------------------------------------------------------------
// TripletContrastiveLoss on MI355X (gfx950)  — Round 11
// Base: R8 (188 µs, passed; tile 103 µs). ONE change: tile K-loop BK 32->64
// (16 steps, 32 MFMAs per barrier). Theory: staging BW (~31 µs) and MFMA
// (~14 µs) don't explain 103 µs — the per-step critical path is load latency
// (~200-900 cyc) vs only ~150 cyc of MFMA cover at BK=32. Doubling work per
// barrier doubles the prefetch window and halves barrier count.
// All other kernels + launcher byte-identical to R8 (both memsets in the
// launcher, slotOf overlays posmin, 256-thread blocks, no global_load_lds).
// ---------------------------------------------------------------------------

#define B_ROWS 8192
#define DIM    1024

typedef __bf16 bf16x8 __attribute__((ext_vector_type(8)));
typedef float  f32x4  __attribute__((ext_vector_type(4)));

__device__ __forceinline__ unsigned short f2bf_rne(float x) {
    unsigned u = __float_as_uint(x);
    unsigned r = (u + 0x7FFFu + ((u >> 16) & 1u)) >> 16;
    return (unsigned short)r;
}
__device__ __forceinline__ float bf2f(unsigned short h) {
    return __uint_as_float(((unsigned)h) << 16);
}

// ---------------------------------------------------------------------------
// Kernel 0: slot assignment via LDS prefix scan. 1 block x 256 threads,
// 32 rows/thread. Zero atomics. slotOf overlays the posmin region (consumed
// by normalize_rows, then clobbered by the 0xFF memset — stream-ordered).
// cnt[0] = nA.
// ---------------------------------------------------------------------------
__global__ __launch_bounds__(256) void compute_slots(
    const int* __restrict__ dom, int* __restrict__ slotOf,
    unsigned* __restrict__ cnt)
{
    __shared__ int cnts[256];
    __shared__ int base[257];
    const int t = threadIdx.x;
    const int p0 = t * 32;

    unsigned mask = 0u; int c = 0;
    #pragma unroll
    for (int i = 0; i < 32; ++i) {
        const int isA = (dom[p0 + i] == 0) ? 1 : 0;
        mask |= ((unsigned)isA) << i;
        c += isA;
    }
    cnts[t] = c;
    __syncthreads();
    if (t == 0) {
        int acc = 0;
        for (int i = 0; i < 256; ++i) { base[i] = acc; acc += cnts[i]; }
        base[256] = acc;
        cnt[0] = (unsigned)acc;                  // nA
    }
    __syncthreads();
    const int nA = base[256];
    int aB = base[t];
    #pragma unroll
    for (int i = 0; i < 32; ++i) {
        const int isA = (mask >> i) & 1;
        slotOf[p0 + i] = isA ? aB : nA + (p0 + i - aB);
        aB += isA;
    }
}

// ---------------------------------------------------------------------------
// Kernel 1: one row per WAVE. 2048 blocks x 256 threads (4 waves). Wave-local
// shuffle reductions only. L2-normalize fp32, round to bf16, scatter to slot.
// sqG[slot] = sum of squares of the bf16-ROUNDED row.
// ---------------------------------------------------------------------------
__global__ __launch_bounds__(256) void normalize_rows(
    const float* __restrict__ feat, const int* __restrict__ labels,
    const int* __restrict__ slotOf, unsigned short* __restrict__ G,
    int* __restrict__ labG, float* __restrict__ sqG)
{
    const int wv = threadIdx.x >> 6, lane = threadIdx.x & 63;
    const int row = blockIdx.x * 4 + wv;

    const float4* src = (const float4*)(feat + (size_t)row * DIM);
    float4 v[4];
    float ss = 0.0f;
    #pragma unroll
    for (int j = 0; j < 4; ++j) {
        v[j] = src[j * 64 + lane];
        ss += v[j].x * v[j].x + v[j].y * v[j].y + v[j].z * v[j].z + v[j].w * v[j].w;
    }
    #pragma unroll
    for (int s = 32; s > 0; s >>= 1) ss += __shfl_xor(ss, s);
    const float inv = 1.0f / fmaxf(sqrtf(ss), 1e-12f);

    const int slot = slotOf[row];
    unsigned short ub[16];
    float ss2 = 0.0f;
    #pragma unroll
    for (int j = 0; j < 4; ++j) {
        const float f0 = v[j].x * inv, f1 = v[j].y * inv,
                    f2 = v[j].z * inv, f3 = v[j].w * inv;
        ub[j * 4 + 0] = f2bf_rne(f0); ub[j * 4 + 1] = f2bf_rne(f1);
        ub[j * 4 + 2] = f2bf_rne(f2); ub[j * 4 + 3] = f2bf_rne(f3);
        #pragma unroll
        for (int q = 0; q < 4; ++q) {
            const float fr = bf2f(ub[j * 4 + q]);
            ss2 += fr * fr;
        }
    }
    #pragma unroll
    for (int s = 32; s > 0; s >>= 1) ss2 += __shfl_xor(ss2, s);
    if (lane == 0) {
        sqG[slot]  = ss2;
        labG[slot] = labels[row];
    }
    ushort4* dst = (ushort4*)(G + (size_t)slot * DIM);
    #pragma unroll
    for (int j = 0; j < 4; ++j) {
        ushort4 pk;
        pk.x = ub[j * 4 + 0]; pk.y = ub[j * 4 + 1];
        pk.z = ub[j * 4 + 2]; pk.w = ub[j * 4 + 3];
        dst[j * 64 + lane] = pk;
    }
}

// ---------------------------------------------------------------------------
// Kernel 2: persistent 128x128 tiles, 4 waves (each 64x64 via 4x4 of
// 16x16x32 bf16 MFMA). K=1024 in 16 steps of BK=64 (two MFMA k-chunks per
// step => 32 MFMAs per barrier, double the prefetch-hiding window of BK=32).
// Double-buffered LDS, row stride 72 shorts (128 B data + 16 B pad; b128
// reads alias 2-way = free). VGPR prefetch of step k+1 (8 x uint4) before
// the MFMAs of step k; ONE barrier per step.
// Epilogue: min d^2 per anchor row -> atomicMin (uint order, d^2 >= 0).
// ---------------------------------------------------------------------------
__global__ __launch_bounds__(256) void tile_mindist(
    const unsigned short* __restrict__ G, const int* __restrict__ labG,
    const float* __restrict__ sqG, const unsigned* __restrict__ cnt,
    unsigned* __restrict__ posmin, unsigned* __restrict__ negmin)
{
    const int nA = (int)cnt[0];
    const int nF = B_ROWS - nA;
    const int nTA = (nA + 127) >> 7;
    const int nTF = (nF + 127) >> 7;
    const int total = nTA * nTF;

    // [buf][A=0/F=1][128 rows x 72 shorts] = 73,728 B
    __shared__ __align__(16) unsigned short S[2][2][128 * 72];

    const int t = threadIdx.x;
    const int lane = t & 63, w = t >> 6;
    const int wm = w >> 1, wn = w & 1;          // wave sub-tile coords (x64)
    const int l15 = lane & 15, quad = lane >> 4;

    // Staging geometry: chunk c (of 1024 per array) = row c>>3, 16B col c&7.
    // Thread t owns chunks t, t+256, t+512, t+768 for BOTH arrays.
    int rowLoc[4], colB[4], lOff[4];
    #pragma unroll
    for (int i = 0; i < 4; ++i) {
        const int c = t + i * 256;
        rowLoc[i] = c >> 3;                      // 0..127
        colB[i]   = (c & 7) * 16;                // byte col within 128-B row
        lOff[i]   = rowLoc[i] * 72 + (c & 7) * 8;  // LDS offset (shorts)
    }
    // Fragment read offsets (shorts); +u*32 shorts for the second k-chunk.
    const int rdA = (wm * 64 + l15) * 72 + quad * 8;
    const int rdF = (wn * 64 + l15) * 72 + quad * 8;

    const char* Gb = (const char*)G;

    for (int tile = blockIdx.x; tile < total; tile += gridDim.x) {
        const int tx = tile % nTA;
        const int ty = tile / nTA;
        const int rowA0 = tx * 128;
        const int rowF0 = nA + ty * 128;

        const char* gA[4]; const char* gF[4];
        #pragma unroll
        for (int i = 0; i < 4; ++i) {
            const int rA = rowA0 + rowLoc[i];                // < 8192 always
            int rF = rowF0 + rowLoc[i];
            if (rF > B_ROWS - 1) rF = B_ROWS - 1;            // clamp; masked later
            gA[i] = Gb + (size_t)rA * (DIM * 2) + colB[i];
            gF[i] = Gb + (size_t)rF * (DIM * 2) + colB[i];
        }

        f32x4 acc[4][4] = {};

        // Prologue: stage K-chunk 0 (128 B rows) into buffer 0.
        #pragma unroll
        for (int i = 0; i < 4; ++i) {
            *(uint4*)&S[0][0][lOff[i]] = *(const uint4*)(gA[i]);
            *(uint4*)&S[0][1][lOff[i]] = *(const uint4*)(gF[i]);
        }
        __syncthreads();

        #pragma unroll 2
        for (int step = 0; step < 16; ++step) {
            const int cur = step & 1;
            const bool has_next = step < 15;
            uint4 na[4], nf[4];
            if (has_next) {                       // prefetch K-chunk step+1
                const int off = (step + 1) * 128;
                #pragma unroll
                for (int i = 0; i < 4; ++i) {
                    na[i] = *(const uint4*)(gA[i] + off);
                    nf[i] = *(const uint4*)(gF[i] + off);
                }
            }

            #pragma unroll
            for (int u = 0; u < 2; ++u) {         // two 32-K chunks
                const unsigned short* pa = &S[cur][0][rdA + u * 32];
                const unsigned short* pf = &S[cur][1][rdF + u * 32];
                bf16x8 a[4], b[4];
                #pragma unroll
                for (int fm = 0; fm < 4; ++fm) a[fm] = *(const bf16x8*)(pa + fm * 1152);
                #pragma unroll
                for (int fn = 0; fn < 4; ++fn) b[fn] = *(const bf16x8*)(pf + fn * 1152);
                #pragma unroll
                for (int fm = 0; fm < 4; ++fm)
                    #pragma unroll
                    for (int fn = 0; fn < 4; ++fn)
                        acc[fm][fn] = __builtin_amdgcn_mfma_f32_16x16x32_bf16(
                            a[fm], b[fn], acc[fm][fn], 0, 0, 0);
            }

            if (has_next) {                       // stage into the other buffer
                const int nb = cur ^ 1;
                #pragma unroll
                for (int i = 0; i < 4; ++i) {
                    *(uint4*)&S[nb][0][lOff[i]] = na[i];
                    *(uint4*)&S[nb][1][lOff[i]] = nf[i];
                }
            }
            __syncthreads();                      // one barrier per step
        }

        // Epilogue. C/D layout: col = lane&15 (field), row = quad*4+reg (anchor).
        const float INFV = __uint_as_float(0x7f800000u);
        float sqf[4]; int lf_[4]; bool vf[4];
        #pragma unroll
        for (int fn = 0; fn < 4; ++fn) {
            const int rf = rowF0 + wn * 64 + fn * 16 + l15;
            vf[fn] = rf < B_ROWS;
            const int rc = vf[fn] ? rf : (B_ROWS - 1);
            sqf[fn] = sqG[rc];
            lf_[fn] = labG[rc];
        }
        #pragma unroll
        for (int fm = 0; fm < 4; ++fm) {
            #pragma unroll
            for (int r = 0; r < 4; ++r) {
                const int ra = rowA0 + wm * 64 + fm * 16 + quad * 4 + r;
                const bool va = ra < nA;
                const int rac = va ? ra : 0;
                const float sqa = sqG[rac];
                const int la_ = labG[rac];
                float pmin = INFV, nmin = INFV;
                #pragma unroll
                for (int fn = 0; fn < 4; ++fn) {
                    const float dd = fmaxf(sqa + sqf[fn] - 2.0f * acc[fm][fn][r], 0.0f);
                    if (vf[fn]) {
                        if (la_ == lf_[fn]) pmin = fminf(pmin, dd);
                        else                nmin = fminf(nmin, dd);
                    }
                }
                #pragma unroll
                for (int s = 1; s < 16; s <<= 1) {
                    pmin = fminf(pmin, __shfl_xor(pmin, s));
                    nmin = fminf(nmin, __shfl_xor(nmin, s));
                }
                if (l15 == 0 && va) {
                    if (pmin < INFV) atomicMin(&posmin[ra], __float_as_uint(pmin));
                    if (nmin < INFV) atomicMin(&negmin[ra], __float_as_uint(nmin));
                }
            }
        }
    }
}

// ---------------------------------------------------------------------------
// Kernel 3: sqrt(d^2 mins) + hinge + sum/count. Untouched slots stay
// 0xFFFFFFFF and drop out as invalid.
// ---------------------------------------------------------------------------
__global__ __launch_bounds__(256) void reduce_loss(
    const unsigned* __restrict__ posmin, const unsigned* __restrict__ negmin,
    float* __restrict__ accum)
{
    const int i = blockIdx.x * 256 + threadIdx.x;
    const unsigned up = posmin[i], un = negmin[i];
    float tl = 0.0f, c = 0.0f;
    if (up != 0xFFFFFFFFu && un != 0xFFFFFFFFu) {
        const float pd = sqrtf(__uint_as_float(up));
        const float nd = sqrtf(__uint_as_float(un));
        tl = fmaxf(pd - nd + 0.3f, 0.0f);
        c = 1.0f;
    }
    #pragma unroll
    for (int s = 32; s > 0; s >>= 1) {
        tl += __shfl_down(tl, s);
        c  += __shfl_down(c, s);
    }
    __shared__ float sb[8];
    const int lane = threadIdx.x & 63, w = threadIdx.x >> 6;
    if (lane == 0) { sb[w] = tl; sb[4 + w] = c; }
    __syncthreads();
    if (threadIdx.x == 0) {
        atomicAdd(&accum[0], sb[0] + sb[1] + sb[2] + sb[3]);
        atomicAdd(&accum[1], sb[4] + sb[5] + sb[6] + sb[7]);
    }
}

__global__ void finalize(const float* __restrict__ accum, float* __restrict__ out) {
    const float s = accum[0], c = accum[1];
    out[0] = (c > 0.0f) ? s / fmaxf(c, 1.0f) : 0.0f;
}

// ---------------------------------------------------------------------------
extern "C" void kernel_launch(void* const* d_in, const int* in_sizes, int n_in,
                              void* d_out, int out_size, void* d_ws, size_t ws_size,
                              hipStream_t stream) {
    const float* feat  = (const float*)d_in[0];
    const int* labels  = (const int*)d_in[1];
    const int* dom     = (const int*)d_in[2];
    float* out = (float*)d_out;

    char* ws = (char*)d_ws;
    // Workspace layout (bytes) — identical footprint to validated R4/R8 layout:
    unsigned short* G   = (unsigned short*)(ws);                 // 16,777,216
    int*      labG      = (int*)(ws + 16777216);                 //     32,768
    float*    sqG       = (float*)(ws + 16809984);               //     32,768
    unsigned* posmin    = (unsigned*)(ws + 16842752);            //     32,768
    unsigned* negmin    = (unsigned*)(ws + 16875520);            //     32,768
    unsigned* cnt       = (unsigned*)(ws + 16908288);            //  8 (nA, unused)
    float*    accum     = (float*)(ws + 16908296);               //  8 (sum, count)
    // slotOf OVERLAYS posmin: written by compute_slots, consumed by
    // normalize_rows, then clobbered by the 0xFF memset (stream-ordered).
    int*      slotOf    = (int*)(ws + 16842752);

    hipMemsetAsync(cnt, 0, 16, stream);             // cnt + accum = 0

    compute_slots<<<1, 256, 0, stream>>>(dom, slotOf, cnt);
    normalize_rows<<<B_ROWS / 4, 256, 0, stream>>>(feat, labels, slotOf,
                                                   G, labG, sqG);

    hipMemsetAsync(posmin, 0xFF, 65536, stream);    // posmin+negmin = +inf bits

    // Max tiles over all nA splits: ceil(a/128)*ceil((8192-a)/128) <= 1056.
    tile_mindist<<<1056, 256, 0, stream>>>(G, labG, sqG, cnt, posmin, negmin);

    reduce_loss<<<B_ROWS / 256, 256, 0, stream>>>(posmin, negmin, accum);
    finalize<<<1, 1, 0, stream>>>(accum, out);
}

// Round 12
// 180.525 us; speedup vs baseline: 1.6264x; 1.6264x over previous
//
#include <hip/hip_runtime.h>

// ---------------------------------------------------------------------------
// TripletContrastiveLoss on MI355X (gfx950)  — Round 12
// Base: R8 (188 µs; tile 103 µs). ONE variable: tile staging switched from
// VGPR-roundtrip uint4 copies to __builtin_amdgcn_global_load_lds width=16
// (the m93->m97 1.69x ladder step), double-buffered unpadded 64 B LDS rows,
// ONE barrier per K-step. R11 taught: >4 live uint4/thread spills (WRITE_SIZE
// 7->296 MB); async staging holds ZERO staging registers. Failure-pattern
// analysis (pairs of failures followed by passes, content-independent)
// un-implicates global_load_lds from the R2/R3 burst.
// All other kernels + launcher byte-identical to R8.
// ---------------------------------------------------------------------------

#define B_ROWS 8192
#define DIM    1024

typedef __bf16 bf16x8 __attribute__((ext_vector_type(8)));
typedef float  f32x4  __attribute__((ext_vector_type(4)));

__device__ __forceinline__ unsigned short f2bf_rne(float x) {
    unsigned u = __float_as_uint(x);
    unsigned r = (u + 0x7FFFu + ((u >> 16) & 1u)) >> 16;
    return (unsigned short)r;
}
__device__ __forceinline__ float bf2f(unsigned short h) {
    return __uint_as_float(((unsigned)h) << 16);
}

// Async global->LDS, 16 B per lane. LDS dest must be wave-uniform; HW places
// lane i at base + 16*i (matches 16 rows x 64 B row-major chunk layout).
__device__ __forceinline__ void async_copy16(const void* g, void* l) {
    __builtin_amdgcn_global_load_lds(
        (const __attribute__((address_space(1))) unsigned int*)g,
        (__attribute__((address_space(3))) unsigned int*)l,
        16, 0, 0);
}

// ---------------------------------------------------------------------------
// Kernel 0: slot assignment via LDS prefix scan. 1 block x 256 threads,
// 32 rows/thread. Zero atomics. slotOf overlays the posmin region (consumed
// by normalize_rows, then clobbered by the 0xFF memset — stream-ordered).
// cnt[0] = nA.
// ---------------------------------------------------------------------------
__global__ __launch_bounds__(256) void compute_slots(
    const int* __restrict__ dom, int* __restrict__ slotOf,
    unsigned* __restrict__ cnt)
{
    __shared__ int cnts[256];
    __shared__ int base[257];
    const int t = threadIdx.x;
    const int p0 = t * 32;

    unsigned mask = 0u; int c = 0;
    #pragma unroll
    for (int i = 0; i < 32; ++i) {
        const int isA = (dom[p0 + i] == 0) ? 1 : 0;
        mask |= ((unsigned)isA) << i;
        c += isA;
    }
    cnts[t] = c;
    __syncthreads();
    if (t == 0) {
        int acc = 0;
        for (int i = 0; i < 256; ++i) { base[i] = acc; acc += cnts[i]; }
        base[256] = acc;
        cnt[0] = (unsigned)acc;                  // nA
    }
    __syncthreads();
    const int nA = base[256];
    int aB = base[t];
    #pragma unroll
    for (int i = 0; i < 32; ++i) {
        const int isA = (mask >> i) & 1;
        slotOf[p0 + i] = isA ? aB : nA + (p0 + i - aB);
        aB += isA;
    }
}

// ---------------------------------------------------------------------------
// Kernel 1: one row per WAVE. 2048 blocks x 256 threads (4 waves). Wave-local
// shuffle reductions only. L2-normalize fp32, round to bf16, scatter to slot.
// sqG[slot] = sum of squares of the bf16-ROUNDED row.
// ---------------------------------------------------------------------------
__global__ __launch_bounds__(256) void normalize_rows(
    const float* __restrict__ feat, const int* __restrict__ labels,
    const int* __restrict__ slotOf, unsigned short* __restrict__ G,
    int* __restrict__ labG, float* __restrict__ sqG)
{
    const int wv = threadIdx.x >> 6, lane = threadIdx.x & 63;
    const int row = blockIdx.x * 4 + wv;

    const float4* src = (const float4*)(feat + (size_t)row * DIM);
    float4 v[4];
    float ss = 0.0f;
    #pragma unroll
    for (int j = 0; j < 4; ++j) {
        v[j] = src[j * 64 + lane];
        ss += v[j].x * v[j].x + v[j].y * v[j].y + v[j].z * v[j].z + v[j].w * v[j].w;
    }
    #pragma unroll
    for (int s = 32; s > 0; s >>= 1) ss += __shfl_xor(ss, s);
    const float inv = 1.0f / fmaxf(sqrtf(ss), 1e-12f);

    const int slot = slotOf[row];
    unsigned short ub[16];
    float ss2 = 0.0f;
    #pragma unroll
    for (int j = 0; j < 4; ++j) {
        const float f0 = v[j].x * inv, f1 = v[j].y * inv,
                    f2 = v[j].z * inv, f3 = v[j].w * inv;
        ub[j * 4 + 0] = f2bf_rne(f0); ub[j * 4 + 1] = f2bf_rne(f1);
        ub[j * 4 + 2] = f2bf_rne(f2); ub[j * 4 + 3] = f2bf_rne(f3);
        #pragma unroll
        for (int q = 0; q < 4; ++q) {
            const float fr = bf2f(ub[j * 4 + q]);
            ss2 += fr * fr;
        }
    }
    #pragma unroll
    for (int s = 32; s > 0; s >>= 1) ss2 += __shfl_xor(ss2, s);
    if (lane == 0) {
        sqG[slot]  = ss2;
        labG[slot] = labels[row];
    }
    ushort4* dst = (ushort4*)(G + (size_t)slot * DIM);
    #pragma unroll
    for (int j = 0; j < 4; ++j) {
        ushort4 pk;
        pk.x = ub[j * 4 + 0]; pk.y = ub[j * 4 + 1];
        pk.z = ub[j * 4 + 2]; pk.w = ub[j * 4 + 3];
        dst[j * 64 + lane] = pk;
    }
}

// ---------------------------------------------------------------------------
// Kernel 2: persistent 128x128 tiles, 4 waves (each 64x64 via 4x4 of
// 16x16x32 bf16 MFMA), K=1024 in 32 steps of BK=32. Staging via
// global_load_lds width=16: each wave issues 4 async copies per step (chunks
// of 16 rows x 64 B), double-buffered unpadded LDS (2x2x8 KB = 32 KB), ONE
// barrier per step. The async loads for step k+1 target the buffer whose
// readers all passed the PREVIOUS barrier; this step's barrier vmcnt-drain
// guarantees completion before step k+1 consumes it.
// Epilogue: min d^2 per anchor row -> atomicMin (uint order, d^2 >= 0).
// ---------------------------------------------------------------------------
__global__ __launch_bounds__(256) void tile_mindist(
    const unsigned short* __restrict__ G, const int* __restrict__ labG,
    const float* __restrict__ sqG, const unsigned* __restrict__ cnt,
    unsigned* __restrict__ posmin, unsigned* __restrict__ negmin)
{
    const int nA = (int)cnt[0];
    const int nF = B_ROWS - nA;
    const int nTA = (nA + 127) >> 7;
    const int nTF = (nF + 127) >> 7;
    const int total = nTA * nTF;

    // [buf][A=0/F=1][128 rows x 32 shorts (64 B, unpadded)] = 32,768 B
    __shared__ __align__(16) unsigned short S[2][2][128 * 32];

    const int t = threadIdx.x;
    const int lane = t & 63, w = t >> 6;
    const int wm = w >> 1, wn = w & 1;          // wave sub-tile coords (x64)
    const int l15 = lane & 15, quad = lane >> 4;

    // Async staging geometry: chunk ch = rows [16ch, 16ch+16); wave w owns
    // chunks 2w and 2w+1 of both arrays. Lane: row 16ch + (lane>>2),
    // byte col (lane&3)*16. LDS base per chunk is wave-uniform.
    const int ch0 = 2 * w;
    const int crow = lane >> 2;
    const int cbyte = (lane & 3) * 16;

    // Fragment read offsets (shorts), row stride 32 shorts.
    const int rdA = (wm * 64 + l15) * 32 + quad * 8;
    const int rdF = (wn * 64 + l15) * 32 + quad * 8;

    const char* Gb = (const char*)G;

    for (int tile = blockIdx.x; tile < total; tile += gridDim.x) {
        const int tx = tile % nTA;
        const int ty = tile / nTA;
        const int rowA0 = tx * 128;
        const int rowF0 = nA + ty * 128;

        const char* ga[2]; const char* gf[2];
        #pragma unroll
        for (int h = 0; h < 2; ++h) {
            const int ch = ch0 + h;
            const int rA = rowA0 + 16 * ch + crow;          // < 8192 always
            int rF = rowF0 + 16 * ch + crow;
            if (rF > B_ROWS - 1) rF = B_ROWS - 1;           // clamp; masked later
            ga[h] = Gb + (size_t)rA * (DIM * 2) + cbyte;
            gf[h] = Gb + (size_t)rF * (DIM * 2) + cbyte;
        }

        f32x4 acc[4][4] = {};

        // Prologue: stage K-chunk 0 into buffer 0.
        #pragma unroll
        for (int h = 0; h < 2; ++h) {
            async_copy16(ga[h], &S[0][0][(ch0 + h) * 512]);
            async_copy16(gf[h], &S[0][1][(ch0 + h) * 512]);
        }
        __syncthreads();                         // drains vmcnt (buf0 ready)

        #pragma unroll 4
        for (int step = 0; step < 32; ++step) {
            const int cur = step & 1;
            const int nb = cur ^ 1;
            if (step < 31) {                     // async-stage step+1 into nb
                const int off = (step + 1) * 64; // 64 B of K per step
                #pragma unroll
                for (int h = 0; h < 2; ++h) {
                    async_copy16(ga[h] + off, &S[nb][0][(ch0 + h) * 512]);
                    async_copy16(gf[h] + off, &S[nb][1][(ch0 + h) * 512]);
                }
            }

            const unsigned short* pa = &S[cur][0][rdA];
            const unsigned short* pf = &S[cur][1][rdF];
            bf16x8 a[4], b[4];
            #pragma unroll
            for (int fm = 0; fm < 4; ++fm) a[fm] = *(const bf16x8*)(pa + fm * 512);
            #pragma unroll
            for (int fn = 0; fn < 4; ++fn) b[fn] = *(const bf16x8*)(pf + fn * 512);
            #pragma unroll
            for (int fm = 0; fm < 4; ++fm)
                #pragma unroll
                for (int fn = 0; fn < 4; ++fn)
                    acc[fm][fn] = __builtin_amdgcn_mfma_f32_16x16x32_bf16(
                        a[fm], b[fn], acc[fm][fn], 0, 0, 0);

            __syncthreads();   // one barrier: completes nb loads, frees cur
        }

        // Epilogue. C/D layout: col = lane&15 (field), row = quad*4+reg (anchor).
        const float INFV = __uint_as_float(0x7f800000u);
        float sqf[4]; int lf_[4]; bool vf[4];
        #pragma unroll
        for (int fn = 0; fn < 4; ++fn) {
            const int rf = rowF0 + wn * 64 + fn * 16 + l15;
            vf[fn] = rf < B_ROWS;
            const int rc = vf[fn] ? rf : (B_ROWS - 1);
            sqf[fn] = sqG[rc];
            lf_[fn] = labG[rc];
        }
        #pragma unroll
        for (int fm = 0; fm < 4; ++fm) {
            #pragma unroll
            for (int r = 0; r < 4; ++r) {
                const int ra = rowA0 + wm * 64 + fm * 16 + quad * 4 + r;
                const bool va = ra < nA;
                const int rac = va ? ra : 0;
                const float sqa = sqG[rac];
                const int la_ = labG[rac];
                float pmin = INFV, nmin = INFV;
                #pragma unroll
                for (int fn = 0; fn < 4; ++fn) {
                    const float dd = fmaxf(sqa + sqf[fn] - 2.0f * acc[fm][fn][r], 0.0f);
                    if (vf[fn]) {
                        if (la_ == lf_[fn]) pmin = fminf(pmin, dd);
                        else                nmin = fminf(nmin, dd);
                    }
                }
                #pragma unroll
                for (int s = 1; s < 16; s <<= 1) {
                    pmin = fminf(pmin, __shfl_xor(pmin, s));
                    nmin = fminf(nmin, __shfl_xor(nmin, s));
                }
                if (l15 == 0 && va) {
                    if (pmin < INFV) atomicMin(&posmin[ra], __float_as_uint(pmin));
                    if (nmin < INFV) atomicMin(&negmin[ra], __float_as_uint(nmin));
                }
            }
        }
        __syncthreads();   // protect LDS before next tile's prologue writes
    }
}

// ---------------------------------------------------------------------------
// Kernel 3: sqrt(d^2 mins) + hinge + sum/count. Untouched slots stay
// 0xFFFFFFFF and drop out as invalid.
// ---------------------------------------------------------------------------
__global__ __launch_bounds__(256) void reduce_loss(
    const unsigned* __restrict__ posmin, const unsigned* __restrict__ negmin,
    float* __restrict__ accum)
{
    const int i = blockIdx.x * 256 + threadIdx.x;
    const unsigned up = posmin[i], un = negmin[i];
    float tl = 0.0f, c = 0.0f;
    if (up != 0xFFFFFFFFu && un != 0xFFFFFFFFu) {
        const float pd = sqrtf(__uint_as_float(up));
        const float nd = sqrtf(__uint_as_float(un));
        tl = fmaxf(pd - nd + 0.3f, 0.0f);
        c = 1.0f;
    }
    #pragma unroll
    for (int s = 32; s > 0; s >>= 1) {
        tl += __shfl_down(tl, s);
        c  += __shfl_down(c, s);
    }
    __shared__ float sb[8];
    const int lane = threadIdx.x & 63, w = threadIdx.x >> 6;
    if (lane == 0) { sb[w] = tl; sb[4 + w] = c; }
    __syncthreads();
    if (threadIdx.x == 0) {
        atomicAdd(&accum[0], sb[0] + sb[1] + sb[2] + sb[3]);
        atomicAdd(&accum[1], sb[4] + sb[5] + sb[6] + sb[7]);
    }
}

__global__ void finalize(const float* __restrict__ accum, float* __restrict__ out) {
    const float s = accum[0], c = accum[1];
    out[0] = (c > 0.0f) ? s / fmaxf(c, 1.0f) : 0.0f;
}

// ---------------------------------------------------------------------------
extern "C" void kernel_launch(void* const* d_in, const int* in_sizes, int n_in,
                              void* d_out, int out_size, void* d_ws, size_t ws_size,
                              hipStream_t stream) {
    const float* feat  = (const float*)d_in[0];
    const int* labels  = (const int*)d_in[1];
    const int* dom     = (const int*)d_in[2];
    float* out = (float*)d_out;

    char* ws = (char*)d_ws;
    // Workspace layout (bytes) — identical footprint to validated R4/R8 layout:
    unsigned short* G   = (unsigned short*)(ws);                 // 16,777,216
    int*      labG      = (int*)(ws + 16777216);                 //     32,768
    float*    sqG       = (float*)(ws + 16809984);               //     32,768
    unsigned* posmin    = (unsigned*)(ws + 16842752);            //     32,768
    unsigned* negmin    = (unsigned*)(ws + 16875520);            //     32,768
    unsigned* cnt       = (unsigned*)(ws + 16908288);            //  8 (nA, unused)
    float*    accum     = (float*)(ws + 16908296);               //  8 (sum, count)
    // slotOf OVERLAYS posmin: written by compute_slots, consumed by
    // normalize_rows, then clobbered by the 0xFF memset (stream-ordered).
    int*      slotOf    = (int*)(ws + 16842752);

    hipMemsetAsync(cnt, 0, 16, stream);             // cnt + accum = 0

    compute_slots<<<1, 256, 0, stream>>>(dom, slotOf, cnt);
    normalize_rows<<<B_ROWS / 4, 256, 0, stream>>>(feat, labels, slotOf,
                                                   G, labG, sqG);

    hipMemsetAsync(posmin, 0xFF, 65536, stream);    // posmin+negmin = +inf bits

    // Max tiles over all nA splits: ceil(a/128)*ceil((8192-a)/128) <= 1056.
    tile_mindist<<<1056, 256, 0, stream>>>(G, labG, sqG, cnt, posmin, negmin);

    reduce_loss<<<B_ROWS / 256, 256, 0, stream>>>(posmin, negmin, accum);
    finalize<<<1, 1, 0, stream>>>(accum, out);
}